// Round 10
// baseline (1613.354 us; speedup 1.0000x reference)
//
#include <hip/hip_runtime.h>
#include <stdint.h>

typedef float f32x4 __attribute__((ext_vector_type(4)));
typedef unsigned int uint;
typedef unsigned long long ull;

#define NB 2048
#define NS 128
#define NI 8
#define NH 256
#define NG 1024   // 4*H
#define NK 50

#define A_SC 16.0f
#define W_SC 32.0f
#define INV_SC (1.0f/(A_SC*W_SC))

// IDM constants
#define DT_    0.1f
#define V_DES_ 12.64798288f
#define T_HW_  0.50284384f
#define A_MAX_ 0.10033688f
#define B_SAFE_ 4.98937183f
#define S0_    0.13082412f

// LDS own-half h buffer: [2][32 rows][128 B]; 16B-granule XOR swizzle (8 granules)
__device__ __forceinline__ int haddr8(int row, int b) {
    return row * 128 + ((((b >> 4) ^ (row & 7)) & 7) << 4) + (b & 15);
}

__device__ __forceinline__ uint8_t f2fp8(float v) {
    int r = __builtin_amdgcn_cvt_pk_fp8_f32(v, v, 0, false);
    return (uint8_t)(r & 0xff);
}
__device__ __forceinline__ float sigm(float x) { return 1.0f / (1.0f + __expf(-x)); }
__device__ __forceinline__ float tanh_f(float x) {
    x = fminf(fmaxf(x, -15.0f), 15.0f);
    float e = __expf(2.0f * x);
    return (e - 1.0f) / (e + 1.0f);
}

// wave-level poll: all lanes load the same counter (one L2 request per iter);
// compiler barrier after exit so data loads are not hoisted above the poll.
#define WPOLL(CP, TGT) do { \
    uint gd_ = 0; \
    while (__hip_atomic_load((CP), __ATOMIC_RELAXED, __HIP_MEMORY_SCOPE_AGENT) < (uint)(TGT)) { \
        __builtin_amdgcn_s_sleep(2); \
        if (++gd_ > (1u << 16)) break; \
    } \
    asm volatile("" ::: "memory"); \
} while (0)

// ---------------- pre-pass kernels (unchanged, r9-proven) ----------------
__global__ void k_pack(const float* __restrict__ W, uint8_t* __restrict__ out,
                       int tiles, int KB, int Nsrc, int Ksrc) {
    int gid = blockIdx.x * 256 + threadIdx.x;
    int total = tiles * KB * 64;
    if (gid >= total) return;
    int lane = gid & 63;
    int kb   = (gid >> 6) % KB;
    int tile = gid / (64 * KB);
    int n = tile * 16 + (lane & 15);
    int kbase = kb * 32 + (lane >> 4) * 8;
    uint64_t wbits = 0;
    #pragma unroll
    for (int jj = 0; jj < 8; ++jj) {
        int kk = kbase + jj;
        float v = (n < Nsrc && kk < Ksrc) ? W[(size_t)n * Ksrc + kk] * W_SC : 0.0f;
        wbits |= ((uint64_t)f2fp8(v)) << (8 * jj);
    }
    *(uint64_t*)(out + (size_t)gid * 8) = wbits;
}

__global__ void k_bias(const float* __restrict__ bih0, const float* __restrict__ bhh0,
                       const float* __restrict__ bih1, const float* __restrict__ bhh1,
                       float* __restrict__ b0, float* __restrict__ b1) {
    int i = blockIdx.x * 256 + threadIdx.x;
    if (i < NG) b0[i] = bih0[i] + bhh0[i];
    else if (i < 2 * NG) b1[i - NG] = bih1[i - NG] + bhh1[i - NG];
}

__global__ void k_x8(const float* __restrict__ x, uint8_t* __restrict__ x8) {
    int i = blockIdx.x * 256 + threadIdx.x;
    if (i < NB * NS * NI) x8[i] = f2fp8(x[i] * A_SC);
}

// -------- dataflow-pipelined LSTM: 64 groups x {A1,A2,C1,C2}, same XCD --------
// A(uh): layer-0 gates for unit-half uh (all 4 gates), 32 rows. Local h0-half
//   recurrence in LDS; partner half read from ring with 1-step slack.
// C(uh): layer-1 likewise; consumes h0(t) stream from A1+A2 rings.
// NO synchronous cluster barrier: producer bumps a counter after publish;
// consumers wave-poll (normally satisfied) and hide the L2 load latency under
// own-half LDS MFMAs. 1 __syncthreads per step (LDS dbuf).
__global__ __launch_bounds__(512, 2)
void k_pipe(const uint8_t* __restrict__ x8,
            const uint8_t* __restrict__ Wih0P, const uint8_t* __restrict__ Whh0P,
            const uint8_t* __restrict__ Wih1P, const uint8_t* __restrict__ Whh1P,
            const uint8_t* __restrict__ WfcP,
            const float* __restrict__ bias0, const float* __restrict__ bias1,
            const float* __restrict__ bfc,
            uint8_t* __restrict__ h0ring, uint8_t* __restrict__ h1ring,
            uint* __restrict__ ctrs, float* __restrict__ out)
{
    __shared__ uint8_t hbuf[2][4096];   // own-half h state, dbuf, haddr8 layout
    __shared__ uint8_t fcbuf[4096];     // FC staging of partner h1(127)

    const int tid  = threadIdx.x;
    const int lane = tid & 63, w = tid >> 6;
    const int lrow = lane & 15, kgrp = lane >> 4;
    const int blk  = blockIdx.x;
    const int xcd = blk & 7, q = blk >> 3;
    const int slot8 = q >> 2, j = q & 3;          // role j: 0=A1,1=A2,2=C1,3=C2
    const int k = xcd + 8 * slot8;                // group 0..63 (4 roles same XCD)
    const int rowbase = k * 32;
    const int roleC = j >> 1, uh = j & 1;

    // ---- pinned weight fragments (AGPR-resident, read HBM once) ----
    // wave w covers tiles T = g*16 + uh*8 + w (g=0..3): units uh*128+w*16+lrow, all gates
    long wX[4][8], wH[4][8];
    #pragma unroll
    for (int g = 0; g < 4; ++g)
        #pragma unroll
        for (int kb = 0; kb < 8; ++kb) { wX[g][kb] = 0; wH[g][kb] = 0; }
    if (roleC) {
        #pragma unroll
        for (int g = 0; g < 4; ++g) {
            const int T = g * 16 + uh * 8 + w;
            #pragma unroll
            for (int kb = 0; kb < 8; ++kb) {
                wX[g][kb] = *(const long*)(Wih1P + (((size_t)T * 8 + kb) * 64 + lane) * 8);
                wH[g][kb] = *(const long*)(Whh1P + (((size_t)T * 8 + kb) * 64 + lane) * 8);
            }
        }
    } else {
        #pragma unroll
        for (int g = 0; g < 4; ++g) {
            const int T = g * 16 + uh * 8 + w;
            wX[g][0] = *(const long*)(Wih0P + ((size_t)T * 64 + lane) * 8);
            #pragma unroll
            for (int kb = 0; kb < 8; ++kb)
                wH[g][kb] = *(const long*)(Whh0P + (((size_t)T * 8 + kb) * 64 + lane) * 8);
        }
    }
    #pragma unroll
    for (int g = 0; g < 4; ++g)
        #pragma unroll
        for (int kb = 0; kb < 8; ++kb)
            asm volatile("" : "+a"(wH[g][kb]), "+a"(wX[g][kb]));

    const float* bsrc = roleC ? bias1 : bias0;
    float bs[4];
    #pragma unroll
    for (int g = 0; g < 4; ++g) bs[g] = bsrc[g * 256 + uh * 128 + w * 16 + lrow];
    float cv[2][4];
    #pragma unroll
    for (int rt = 0; rt < 2; ++rt)
        #pragma unroll
        for (int r = 0; r < 4; ++r) cv[rt][r] = 0.0f;

    // rings: [group][half][slot(4)][32 rows][128 B]
    uint8_t* const myring = (roleC ? h1ring : h0ring) + ((size_t)(k * 2 + uh) * 4) * 4096;
    const uint8_t* const pring = (roleC ? h1ring : h0ring) + ((size_t)(k * 2 + (uh ^ 1)) * 4) * 4096;
    const uint8_t* const a1ring = h0ring + ((size_t)(k * 2 + 0) * 4) * 4096;
    const uint8_t* const a2ring = h0ring + ((size_t)(k * 2 + 1) * 4) * 4096;
    uint* const cbase = ctrs + k * 64;
    uint* const myctr = cbase + j * 16;
    uint* const pctr  = cbase + (j ^ 1) * 16;
    uint* const cA1 = cbase, * const cA2 = cbase + 16;
    uint* const cC1 = cbase + 32, * const cC2 = cbase + 48;

    const int ul = w * 16 + lrow;                 // lane's local unit
    const int rdoff = kgrp * 8;                   // 8B sub-offset within 32B k-block

    for (int t = 0; t < NS; ++t) {
        const int sl = t & 3;
        f32x4 acc[4][2];
        #pragma unroll
        for (int g = 0; g < 4; ++g) { acc[g][0] = (f32x4){0,0,0,0}; acc[g][1] = (f32x4){0,0,0,0}; }

        if (!roleC) {
            // ===== A: layer 0 =====
            if (t >= 4 && (t & 1) == 0) { WPOLL(cC1, t - 2); WPOLL(cC2, t - 2); }  // ring-overwrite throttle
            #pragma unroll
            for (int rt = 0; rt < 2; ++rt) {
                long ax = 0;
                if (kgrp == 0) ax = *(const long*)(x8 + (size_t)(rowbase + rt * 16 + lrow) * (NS * NI) + t * 8);
                #pragma unroll
                for (int g = 0; g < 4; ++g)
                    acc[g][rt] = __builtin_amdgcn_mfma_f32_16x16x32_fp8_fp8(ax, wX[g][0], acc[g][rt], 0, 0, 0);
            }
            if (t >= 1) {
                WPOLL(pctr, t);   // partner h0-half(t-1) published
                const uint8_t* s1 = pring + (size_t)((t - 1) & 3) * 4096;
                ull pf[2][4];
                #pragma unroll
                for (int rt = 0; rt < 2; ++rt) {
                    const int ro = (rt * 16 + lrow) * 128 + rdoff;
                    #pragma unroll
                    for (int kb = 0; kb < 4; ++kb)
                        pf[rt][kb] = __hip_atomic_load((const ull*)(s1 + ro + kb * 32),
                                                       __ATOMIC_RELAXED, __HIP_MEMORY_SCOPE_AGENT);
                }
                const uint8_t* ob = hbuf[(t + 1) & 1];   // own half h0(t-1)
                #pragma unroll
                for (int kb = 0; kb < 4; ++kb)
                    #pragma unroll
                    for (int rt = 0; rt < 2; ++rt) {
                        long v = *(const long*)&ob[haddr8(rt * 16 + lrow, kb * 32 + rdoff)];
                        #pragma unroll
                        for (int g = 0; g < 4; ++g)
                            acc[g][rt] = __builtin_amdgcn_mfma_f32_16x16x32_fp8_fp8(v, wH[g][uh * 4 + kb], acc[g][rt], 0, 0, 0);
                    }
                #pragma unroll
                for (int kb = 0; kb < 4; ++kb)
                    #pragma unroll
                    for (int rt = 0; rt < 2; ++rt)
                        #pragma unroll
                        for (int g = 0; g < 4; ++g)
                            acc[g][rt] = __builtin_amdgcn_mfma_f32_16x16x32_fp8_fp8((long)pf[rt][kb], wH[g][(uh ^ 1) * 4 + kb], acc[g][rt], 0, 0, 0);
            }
        } else {
            // ===== C: layer 1 =====
            WPOLL(cA1, t + 1);
            WPOLL(cA2, t + 1);
            const uint8_t* s0a = a1ring + (size_t)sl * 4096;
            const uint8_t* s0b = a2ring + (size_t)sl * 4096;
            ull f0[2][8];
            #pragma unroll
            for (int rt = 0; rt < 2; ++rt) {
                const int ro = (rt * 16 + lrow) * 128 + rdoff;
                #pragma unroll
                for (int kb = 0; kb < 4; ++kb) {
                    f0[rt][kb]     = __hip_atomic_load((const ull*)(s0a + ro + kb * 32),
                                                       __ATOMIC_RELAXED, __HIP_MEMORY_SCOPE_AGENT);
                    f0[rt][4 + kb] = __hip_atomic_load((const ull*)(s0b + ro + kb * 32),
                                                       __ATOMIC_RELAXED, __HIP_MEMORY_SCOPE_AGENT);
                }
            }
            ull f1[2][4];
            if (t >= 1) {
                WPOLL(pctr, t);   // partner h1-half(t-1)
                const uint8_t* s1 = pring + (size_t)((t - 1) & 3) * 4096;
                #pragma unroll
                for (int rt = 0; rt < 2; ++rt) {
                    const int ro = (rt * 16 + lrow) * 128 + rdoff;
                    #pragma unroll
                    for (int kb = 0; kb < 4; ++kb)
                        f1[rt][kb] = __hip_atomic_load((const ull*)(s1 + ro + kb * 32),
                                                       __ATOMIC_RELAXED, __HIP_MEMORY_SCOPE_AGENT);
                }
                const uint8_t* ob = hbuf[(t + 1) & 1];   // own half h1(t-1)
                #pragma unroll
                for (int kb = 0; kb < 4; ++kb)
                    #pragma unroll
                    for (int rt = 0; rt < 2; ++rt) {
                        long v = *(const long*)&ob[haddr8(rt * 16 + lrow, kb * 32 + rdoff)];
                        #pragma unroll
                        for (int g = 0; g < 4; ++g)
                            acc[g][rt] = __builtin_amdgcn_mfma_f32_16x16x32_fp8_fp8(v, wH[g][uh * 4 + kb], acc[g][rt], 0, 0, 0);
                    }
            }
            #pragma unroll
            for (int kb = 0; kb < 8; ++kb)
                #pragma unroll
                for (int rt = 0; rt < 2; ++rt)
                    #pragma unroll
                    for (int g = 0; g < 4; ++g)
                        acc[g][rt] = __builtin_amdgcn_mfma_f32_16x16x32_fp8_fp8((long)f0[rt][kb], wX[g][kb], acc[g][rt], 0, 0, 0);
            if (t >= 1) {
                #pragma unroll
                for (int kb = 0; kb < 4; ++kb)
                    #pragma unroll
                    for (int rt = 0; rt < 2; ++rt)
                        #pragma unroll
                        for (int g = 0; g < 4; ++g)
                            acc[g][rt] = __builtin_amdgcn_mfma_f32_16x16x32_fp8_fp8((long)f1[rt][kb], wH[g][(uh ^ 1) * 4 + kb], acc[g][rt], 0, 0, 0);
            }
        }

        // ===== in-register nonlin (r9-proven) + publish to LDS dbuf + ring =====
        {
            uint8_t* ring = myring + (size_t)sl * 4096;
            uint8_t* lb = hbuf[t & 1];
            #pragma unroll
            for (int rt = 0; rt < 2; ++rt)
                #pragma unroll
                for (int r = 0; r < 4; ++r) {
                    const int row = rt * 16 + kgrp * 4 + r;
                    float iv = fmaf(acc[0][rt][r], INV_SC, bs[0]);
                    float fv = fmaf(acc[1][rt][r], INV_SC, bs[1]);
                    float gv = fmaf(acc[2][rt][r], INV_SC, bs[2]);
                    float ov = fmaf(acc[3][rt][r], INV_SC, bs[3]);
                    float c = sigm(fv) * cv[rt][r] + sigm(iv) * tanh_f(gv);
                    cv[rt][r] = c;
                    float hh = sigm(ov) * tanh_f(c);
                    uint8_t b8 = f2fp8(hh * A_SC);
                    lb[haddr8(row, ul)] = b8;
                    __hip_atomic_store(ring + row * 128 + ul, b8,
                                       __ATOMIC_RELAXED, __HIP_MEMORY_SCOPE_AGENT);
                }
        }
        __syncthreads();   // drains ring stores (vmcnt 0) + LDS dbuf visibility
        if (tid == 0)
            __hip_atomic_fetch_add(myctr, 1u, __ATOMIC_RELAXED, __HIP_MEMORY_SCOPE_AGENT);
    }

    // ===== FC head (C roles): y = h1(127) @ Wfc^T + bfc =====
    if (roleC) {
        WPOLL(pctr, NS);   // partner h1(127) published (slot 127&3 = 3)
        {
            const uint8_t* src = pring + (size_t)3 * 4096;
            int row = tid & 31, sg = tid >> 5;   // 16 segs x 8B
            ull v = __hip_atomic_load((const ull*)(src + row * 128 + sg * 8),
                                      __ATOMIC_RELAXED, __HIP_MEMORY_SCOPE_AGENT);
            *(ull*)&fcbuf[haddr8(row, sg * 8)] = v;
        }
        __syncthreads();
        if (w < 2) {
            const int T = uh * 2 + w;            // Wfc tile (cols T*16..)
            f32x4 a2[2];
            a2[0] = (f32x4){0,0,0,0}; a2[1] = (f32x4){0,0,0,0};
            #pragma unroll
            for (int kb = 0; kb < 8; ++kb) {
                const int half_ = kb >> 2, kb_ = kb & 3;
                long bf = *(const long*)(WfcP + (((size_t)T * 8 + kb) * 64 + lane) * 8);
                #pragma unroll
                for (int rt = 0; rt < 2; ++rt) {
                    const uint8_t* src = (half_ == uh) ? hbuf[1] : fcbuf;  // h1(127) own half is hbuf[127&1]
                    long v = *(const long*)&src[haddr8(rt * 16 + lrow, kb_ * 32 + rdoff)];
                    a2[rt] = __builtin_amdgcn_mfma_f32_16x16x32_fp8_fp8(v, bf, a2[rt], 0, 0, 0);
                }
            }
            const int col = T * 16 + lrow;
            if (col < NK) {
                float bb = bfc[col];
                #pragma unroll
                for (int rt = 0; rt < 2; ++rt)
                    #pragma unroll
                    for (int r = 0; r < 4; ++r)
                        out[(size_t)(rowbase + rt * 16 + kgrp * 4 + r) * NK + col] = a2[rt][r] * INV_SC + bb;
            }
        }
    }
}

// ---------------- IDM rollout (exact fp32) ----------------
__global__ void k_idm(const float* __restrict__ x, const float* __restrict__ s0,
                      const float* __restrict__ vl, float* __restrict__ out) {
    int b = blockIdx.x * 256 + threadIdx.x;
    if (b >= NB) return;
    float v = x[(size_t)b * NS * NI + (NS - 1) * NI + 0];
    float s = s0[b];
    float vlead = vl[b];
    const float den = 2.0f * sqrtf(A_MAX_ * B_SAFE_) + 1e-6f;
    float* o = out + (size_t)NB * NK + (size_t)b * NK;
    #pragma unroll 1
    for (int kk = 0; kk < NK; ++kk) {
        float dv = vlead - v;
        float sc = fmaxf(s, 1e-6f);
        float ss = fmaxf(S0_ + v * T_HW_ + v * dv / den, 0.0f);
        float a = A_MAX_ * (1.0f - v / V_DES_ - (ss / sc) * (ss / sc));
        v = fmaxf(v + DT_ * a, 0.0f);
        s = fmaxf(s + dv * DT_, 1e-6f);
        o[kk] = v;
    }
}

// ---------------- launch ----------------
extern "C" void kernel_launch(void* const* d_in, const int* in_sizes, int n_in,
                              void* d_out, int out_size, void* d_ws, size_t ws_size,
                              hipStream_t stream) {
    const float* x    = (const float*)d_in[0];
    const float* s0   = (const float*)d_in[1];
    const float* vl   = (const float*)d_in[2];
    const float* Wih0 = (const float*)d_in[3];
    const float* Whh0 = (const float*)d_in[4];
    const float* bih0 = (const float*)d_in[5];
    const float* bhh0 = (const float*)d_in[6];
    const float* Wih1 = (const float*)d_in[7];
    const float* Whh1 = (const float*)d_in[8];
    const float* bih1 = (const float*)d_in[9];
    const float* bhh1 = (const float*)d_in[10];
    const float* Wfc  = (const float*)d_in[11];
    const float* bfc  = (const float*)d_in[12];
    float* out = (float*)d_out;

    uint8_t* ws = (uint8_t*)d_ws;
    size_t off = 0;
    auto alloc = [&](size_t n) { uint8_t* p = ws + off; off += (n + 255) & ~(size_t)255; return p; };
    uint8_t* Wih0P = alloc(64 * 1 * 64 * 8);
    uint8_t* Whh0P = alloc(64 * 8 * 64 * 8);
    uint8_t* Wih1P = alloc(64 * 8 * 64 * 8);
    uint8_t* Whh1P = alloc(64 * 8 * 64 * 8);
    uint8_t* WfcP  = alloc(4 * 8 * 64 * 8);
    float* b0 = (float*)alloc(NG * 4);
    float* b1 = (float*)alloc(NG * 4);
    uint8_t* x8 = alloc((size_t)NB * NS * NI);
    // rings: [64 groups][2 halves][4 slots][32 rows][128 B] per layer
    uint8_t* h0ring = alloc((size_t)64 * 2 * 4 * 4096);
    uint8_t* h1ring = alloc((size_t)64 * 2 * 4 * 4096);
    uint*    ctrs   = (uint*)alloc(64 * 64 * 4);

    k_pack<<<(64 * 1 * 64 + 255) / 256, 256, 0, stream>>>(Wih0, Wih0P, 64, 1, NG, NI);
    k_pack<<<(64 * 8 * 64 + 255) / 256, 256, 0, stream>>>(Whh0, Whh0P, 64, 8, NG, NH);
    k_pack<<<(64 * 8 * 64 + 255) / 256, 256, 0, stream>>>(Wih1, Wih1P, 64, 8, NG, NH);
    k_pack<<<(64 * 8 * 64 + 255) / 256, 256, 0, stream>>>(Whh1, Whh1P, 64, 8, NG, NH);
    k_pack<<<(4 * 8 * 64 + 255) / 256, 256, 0, stream>>>(Wfc, WfcP, 4, 8, NK, NH);
    k_bias<<<(2 * NG + 255) / 256, 256, 0, stream>>>(bih0, bhh0, bih1, bhh1, b0, b1);
    k_x8<<<(NB * NS * NI + 255) / 256, 256, 0, stream>>>(x, x8);
    hipMemsetAsync(ctrs, 0, 64 * 64 * 4, stream);

    void* kargs[] = { (void*)&x8, (void*)&Wih0P, (void*)&Whh0P, (void*)&Wih1P, (void*)&Whh1P,
                      (void*)&WfcP, (void*)&b0, (void*)&b1, (void*)&bfc,
                      (void*)&h0ring, (void*)&h1ring, (void*)&ctrs, (void*)&out };
    hipError_t ce = hipLaunchCooperativeKernel((const void*)k_pipe, dim3(256), dim3(512), kargs, 0, stream);
    if (ce != hipSuccess) {
        k_pipe<<<256, 512, 0, stream>>>(x8, Wih0P, Whh0P, Wih1P, Whh1P, WfcP, b0, b1, bfc, h0ring, h1ring, ctrs, out);
    }
    k_idm<<<(NB + 255) / 256, 256, 0, stream>>>(x, s0, vl, out);
}

// Round 11
// 942.486 us; speedup vs baseline: 1.7118x; 1.7118x over previous
//
#include <hip/hip_runtime.h>
#include <stdint.h>

typedef float f32x4 __attribute__((ext_vector_type(4)));
typedef long long2_t __attribute__((ext_vector_type(2)));
typedef unsigned int uint;
typedef unsigned long long ull;

#define NB 2048
#define NS 128
#define NI 8
#define NH 256
#define NG 1024   // 4*H
#define NK 50

#define A_SC 16.0f
#define W_SC 32.0f
#define INV_SC (1.0f/(A_SC*W_SC))

#define RING_D 16

// IDM constants
#define DT_    0.1f
#define V_DES_ 12.64798288f
#define T_HW_  0.50284384f
#define A_MAX_ 0.10033688f
#define B_SAFE_ 4.98937183f
#define S0_    0.13082412f

// LDS h stage [16 rows][256 B], 16B-granule XOR swizzle (r9-proven pattern)
__device__ __forceinline__ int HADDR(int row, int boff) {
    return row * 256 + ((((boff >> 4) ^ row) & 15) << 4) + (boff & 15);
}
// byte offset of unit u within a row in A-fragment order [kgrp][kb][8B]
__device__ __forceinline__ int BOFFU(int u) {
    return ((u >> 3) & 3) * 64 + (u >> 5) * 8 + (u & 7);
}

__device__ __forceinline__ uint8_t f2fp8(float v) {
    int r = __builtin_amdgcn_cvt_pk_fp8_f32(v, v, 0, false);
    return (uint8_t)(r & 0xff);
}
__device__ __forceinline__ float sigm(float x) { return 1.0f / (1.0f + __expf(-x)); }
__device__ __forceinline__ float tanh_f(float x) {
    x = fminf(fmaxf(x, -15.0f), 15.0f);
    float e = __expf(2.0f * x);
    return (e - 1.0f) / (e + 1.0f);
}

#define WPOLL(CP, TGT) do { \
    uint gd_ = 0; \
    while (__hip_atomic_load((CP), __ATOMIC_RELAXED, __HIP_MEMORY_SCOPE_AGENT) < (uint)(TGT)) { \
        __builtin_amdgcn_s_sleep(2); \
        if (++gd_ > (1u << 22)) break; \
    } \
    asm volatile("" ::: "memory"); \
} while (0)

// ---------------- pre-pass kernels ----------------
__global__ void k_pack(const float* __restrict__ W, uint8_t* __restrict__ out,
                       int tiles, int KB, int Nsrc, int Ksrc) {
    int gid = blockIdx.x * 256 + threadIdx.x;
    int total = tiles * KB * 64;
    if (gid >= total) return;
    int lane = gid & 63;
    int kb   = (gid >> 6) % KB;
    int tile = gid / (64 * KB);
    int n = tile * 16 + (lane & 15);
    int kbase = kb * 32 + (lane >> 4) * 8;
    uint64_t wbits = 0;
    #pragma unroll
    for (int jj = 0; jj < 8; ++jj) {
        int kk = kbase + jj;
        float v = (n < Nsrc && kk < Ksrc) ? W[(size_t)n * Ksrc + kk] * W_SC : 0.0f;
        wbits |= ((uint64_t)f2fp8(v)) << (8 * jj);
    }
    *(uint64_t*)(out + (size_t)gid * 8) = wbits;
}

__global__ void k_bias(const float* __restrict__ bih0, const float* __restrict__ bhh0,
                       const float* __restrict__ bih1, const float* __restrict__ bhh1,
                       float* __restrict__ b0, float* __restrict__ b1) {
    int i = blockIdx.x * 256 + threadIdx.x;
    if (i < NG) b0[i] = bih0[i] + bhh0[i];
    else if (i < 2 * NG) b1[i - NG] = bih1[i - NG] + bhh1[i - NG];
}

__global__ void k_x8(const float* __restrict__ x, uint8_t* __restrict__ x8) {
    int i = blockIdx.x * 256 + threadIdx.x;
    if (i < NB * NS * NI) x8[i] = f2fp8(x[i] * A_SC);
}

// --------- layer-split pipelined LSTM: CU-local recurrences, acyclic stream ---------
// 256 WGs: blocks 0..127 = L0 (rows 16k..16k+15, Wih0+Whh0 in AGPRs, h0 chain
// in own LDS); blocks 128..255 = L1 (same rows, Whh1 in AGPRs + Wih1 half AGPR
// half LDS, h1 chain in own LDS). Only cross-CU edge: h0(t) ring L0_k -> L1_k
// (same XCD since 128%8==0), depth 16, prefetched 1 step ahead. Acyclic: no
// rendezvous, no cooperative launch needed.
__global__ __launch_bounds__(512, 2)
void k_lpipe(const uint8_t* __restrict__ x8,
             const uint8_t* __restrict__ Wih0P, const uint8_t* __restrict__ Whh0P,
             const uint8_t* __restrict__ Wih1P, const uint8_t* __restrict__ Whh1P,
             const uint8_t* __restrict__ WfcP,
             const float* __restrict__ bias0, const float* __restrict__ bias1,
             const float* __restrict__ bfc,
             uint8_t* __restrict__ ring, uint* __restrict__ ctrs,
             float* __restrict__ out)
{
    __shared__ uint8_t wlds[131072];   // L1: Wih1 kb4..7 frags [wave][tile][kb4][lane*8]
    __shared__ uint8_t hA[2][4096];    // h0 stage (L0: own chain; L1: consumed stream)
    __shared__ uint8_t hB[2][4096];    // L1: h1 chain
    __shared__ float blds[1024];       // L1: bias1 (keeps VGPRs under 256)

    const int tid  = threadIdx.x;
    const int lane = tid & 63, w = tid >> 6;
    const int lrow = lane & 15, kgrp = lane >> 4;
    const int role = blockIdx.x >> 7, k = blockIdx.x & 127;
    uint* const cL0 = ctrs + k * 32;
    uint* const cL1 = ctrs + k * 32 + 16;
    uint8_t* const myring = ring + (size_t)k * RING_D * 4096;

    float cv[2][4];
    #pragma unroll
    for (int j = 0; j < 2; ++j)
        #pragma unroll
        for (int r = 0; r < 4; ++r) cv[j][r] = 0.0f;

    if (role == 0) {
        // ================= L0: layer-0, fully CU-local recurrence =================
        long wx0[8], wh0[8][8];
        #pragma unroll
        for (int ti = 0; ti < 8; ++ti) {
            const int T = (ti >> 1) * 16 + 2 * w + (ti & 1);
            wx0[ti] = *(const long*)(Wih0P + ((size_t)T * 64 + lane) * 8);
            #pragma unroll
            for (int kb = 0; kb < 8; ++kb)
                wh0[ti][kb] = *(const long*)(Whh0P + (((size_t)T * 8 + kb) * 64 + lane) * 8);
        }
        #pragma unroll
        for (int ti = 0; ti < 8; ++ti) {
            asm volatile("" : "+a"(wx0[ti]));
            #pragma unroll
            for (int kb = 0; kb < 8; ++kb) asm volatile("" : "+a"(wh0[ti][kb]));
        }
        float bs[4][2];
        #pragma unroll
        for (int g = 0; g < 4; ++g)
            #pragma unroll
            for (int j = 0; j < 2; ++j)
                bs[g][j] = bias0[g * 256 + (2 * w + j) * 16 + lrow];
        if (tid < 256) { int4 z = {0,0,0,0}; *(int4*)&hA[0][tid * 16] = z; }
        __syncthreads();

        for (int t = 0; t < NS; ++t) {
            if (t >= RING_D) WPOLL(cL1, t - RING_D + 1);   // ring overwrite throttle
            const int buf = t & 1;
            long xf = 0;
            if (kgrp == 0) xf = *(const long*)(x8 + (size_t)(k * 16 + lrow) * (NS * NI) + t * 8);
            f32x4 acc[4][2];
            #pragma unroll
            for (int g = 0; g < 4; ++g) { acc[g][0] = (f32x4){0,0,0,0}; acc[g][1] = (f32x4){0,0,0,0}; }
            #pragma unroll
            for (int ti = 0; ti < 8; ++ti)
                acc[ti >> 1][ti & 1] = __builtin_amdgcn_mfma_f32_16x16x32_fp8_fp8(xf, wx0[ti], acc[ti >> 1][ti & 1], 0, 0, 0);
            #pragma unroll
            for (int kbh = 0; kbh < 4; ++kbh) {
                const int gsw = ((((kgrp << 2) + kbh) ^ lrow) & 15) << 4;
                long2_t q = *(const long2_t*)&hA[buf][lrow * 256 + gsw];
                #pragma unroll
                for (int ti = 0; ti < 8; ++ti) {
                    acc[ti >> 1][ti & 1] = __builtin_amdgcn_mfma_f32_16x16x32_fp8_fp8(q.x, wh0[ti][2 * kbh],     acc[ti >> 1][ti & 1], 0, 0, 0);
                    acc[ti >> 1][ti & 1] = __builtin_amdgcn_mfma_f32_16x16x32_fp8_fp8(q.y, wh0[ti][2 * kbh + 1], acc[ti >> 1][ti & 1], 0, 0, 0);
                }
            }
            // in-register nonlin -> own LDS stage + ring publish
            uint8_t* slot = myring + (size_t)(t & (RING_D - 1)) * 4096;
            #pragma unroll
            for (int j = 0; j < 2; ++j) {
                const int u = (2 * w + j) * 16 + lrow;
                const int bo = BOFFU(u);
                #pragma unroll
                for (int r = 0; r < 4; ++r) {
                    float iv = fmaf(acc[0][j][r], INV_SC, bs[0][j]);
                    float fv = fmaf(acc[1][j][r], INV_SC, bs[1][j]);
                    float gv = fmaf(acc[2][j][r], INV_SC, bs[2][j]);
                    float ov = fmaf(acc[3][j][r], INV_SC, bs[3][j]);
                    float c = sigm(fv) * cv[j][r] + sigm(iv) * tanh_f(gv);
                    cv[j][r] = c;
                    float hh = sigm(ov) * tanh_f(c);
                    uint8_t b8 = f2fp8(hh * A_SC);
                    const int row = kgrp * 4 + r;
                    hA[buf ^ 1][HADDR(row, bo)] = b8;
                    __hip_atomic_store(slot + row * 256 + bo, b8,
                                       __ATOMIC_RELAXED, __HIP_MEMORY_SCOPE_AGENT);
                }
            }
            __syncthreads();   // drains ring stores + LDS stage visible
            if (tid == 0) __hip_atomic_fetch_add(cL0, 1u, __ATOMIC_RELAXED, __HIP_MEMORY_SCOPE_AGENT);
        }
        return;
    }

    // ================= L1: layer-1, consumes h0 stream =================
    long wh1[8][8], wi1a[8][4];
    #pragma unroll
    for (int ti = 0; ti < 8; ++ti) {
        const int T = (ti >> 1) * 16 + 2 * w + (ti & 1);
        #pragma unroll
        for (int kb = 0; kb < 8; ++kb)
            wh1[ti][kb] = *(const long*)(Whh1P + (((size_t)T * 8 + kb) * 64 + lane) * 8);
        #pragma unroll
        for (int kb = 0; kb < 4; ++kb)
            wi1a[ti][kb] = *(const long*)(Wih1P + (((size_t)T * 8 + kb) * 64 + lane) * 8);
        #pragma unroll
        for (int kb = 4; kb < 8; ++kb)
            *(long*)&wlds[w * 16384 + (ti * 4 + kb - 4) * 512 + lane * 8] =
                *(const long*)(Wih1P + (((size_t)T * 8 + kb) * 64 + lane) * 8);
    }
    #pragma unroll
    for (int ti = 0; ti < 8; ++ti) {
        #pragma unroll
        for (int kb = 0; kb < 8; ++kb) asm volatile("" : "+a"(wh1[ti][kb]));
        #pragma unroll
        for (int kb = 0; kb < 4; ++kb) asm volatile("" : "+a"(wi1a[ti][kb]));
    }
    blds[tid] = bias1[tid];
    blds[512 + tid] = bias1[512 + tid];
    if (tid < 256) { int4 z = {0,0,0,0}; *(int4*)&hB[0][tid * 16] = z; }
    __syncthreads();

    // initial stage: h0(0) -> hA[0]
    WPOLL(cL0, 1);
    if (tid < 256) {
        const int row = tid >> 4, s = tid & 15;
        const uint8_t* src = myring + row * 256 + s * 16;
        ull v0 = __hip_atomic_load((const ull*)src,       __ATOMIC_RELAXED, __HIP_MEMORY_SCOPE_AGENT);
        ull v1 = __hip_atomic_load((const ull*)(src + 8), __ATOMIC_RELAXED, __HIP_MEMORY_SCOPE_AGENT);
        const int d = HADDR(row, s * 16);
        *(ull*)&hA[0][d] = v0;
        *(ull*)&hA[0][d + 8] = v1;
    }
    __syncthreads();

    for (int t = 0; t < NS; ++t) {
        const int buf = t & 1;
        // prefetch h0(t+1) into hA[buf^1] (poll normally satisfied: L0 runs ahead)
        if (t < NS - 1) {
            WPOLL(cL0, t + 2);
            if (tid < 256) {
                const int row = tid >> 4, s = tid & 15;
                const uint8_t* src = myring + (size_t)((t + 1) & (RING_D - 1)) * 4096 + row * 256 + s * 16;
                ull v0 = __hip_atomic_load((const ull*)src,       __ATOMIC_RELAXED, __HIP_MEMORY_SCOPE_AGENT);
                ull v1 = __hip_atomic_load((const ull*)(src + 8), __ATOMIC_RELAXED, __HIP_MEMORY_SCOPE_AGENT);
                const int d = HADDR(row, s * 16);
                *(ull*)&hA[buf ^ 1][d] = v0;
                *(ull*)&hA[buf ^ 1][d + 8] = v1;
            }
        }
        f32x4 acc[4][2];
        #pragma unroll
        for (int g = 0; g < 4; ++g) { acc[g][0] = (f32x4){0,0,0,0}; acc[g][1] = (f32x4){0,0,0,0}; }
        #pragma unroll
        for (int kbh = 0; kbh < 4; ++kbh) {
            const int gsw = ((((kgrp << 2) + kbh) ^ lrow) & 15) << 4;
            long2_t q0 = *(const long2_t*)&hA[buf][lrow * 256 + gsw];   // h0(t)
            long2_t q1 = *(const long2_t*)&hB[buf][lrow * 256 + gsw];   // h1(t-1)
            #pragma unroll
            for (int ti = 0; ti < 8; ++ti) {
                long fa, fb;
                if (kbh < 2) { fa = wi1a[ti][2 * kbh]; fb = wi1a[ti][2 * kbh + 1]; }
                else {
                    fa = *(const long*)&wlds[w * 16384 + (ti * 4 + 2 * kbh - 4) * 512 + lane * 8];
                    fb = *(const long*)&wlds[w * 16384 + (ti * 4 + 2 * kbh - 3) * 512 + lane * 8];
                }
                acc[ti >> 1][ti & 1] = __builtin_amdgcn_mfma_f32_16x16x32_fp8_fp8(q0.x, fa, acc[ti >> 1][ti & 1], 0, 0, 0);
                acc[ti >> 1][ti & 1] = __builtin_amdgcn_mfma_f32_16x16x32_fp8_fp8(q0.y, fb, acc[ti >> 1][ti & 1], 0, 0, 0);
                acc[ti >> 1][ti & 1] = __builtin_amdgcn_mfma_f32_16x16x32_fp8_fp8(q1.x, wh1[ti][2 * kbh],     acc[ti >> 1][ti & 1], 0, 0, 0);
                acc[ti >> 1][ti & 1] = __builtin_amdgcn_mfma_f32_16x16x32_fp8_fp8(q1.y, wh1[ti][2 * kbh + 1], acc[ti >> 1][ti & 1], 0, 0, 0);
            }
        }
        // in-register nonlin -> hB[buf^1]
        #pragma unroll
        for (int j = 0; j < 2; ++j) {
            const int u = (2 * w + j) * 16 + lrow;
            const int bo = BOFFU(u);
            #pragma unroll
            for (int r = 0; r < 4; ++r) {
                float iv = fmaf(acc[0][j][r], INV_SC, blds[u]);
                float fv = fmaf(acc[1][j][r], INV_SC, blds[256 + u]);
                float gv = fmaf(acc[2][j][r], INV_SC, blds[512 + u]);
                float ov = fmaf(acc[3][j][r], INV_SC, blds[768 + u]);
                float c = sigm(fv) * cv[j][r] + sigm(iv) * tanh_f(gv);
                cv[j][r] = c;
                float hh = sigm(ov) * tanh_f(c);
                hB[buf ^ 1][HADDR(kgrp * 4 + r, bo)] = f2fp8(hh * A_SC);
            }
        }
        __syncthreads();   // stage loads drained + hB visible
        if (tid == 0) __hip_atomic_fetch_add(cL1, 1u, __ATOMIC_RELAXED, __HIP_MEMORY_SCOPE_AGENT);
    }

    // ===== FC head: y = h1(127) @ Wfc^T + bfc ; h1(127) in hB[0] =====
    if (w < 4) {
        f32x4 a = {0,0,0,0};
        #pragma unroll
        for (int kbh = 0; kbh < 4; ++kbh) {
            const int gsw = ((((kgrp << 2) + kbh) ^ lrow) & 15) << 4;
            long2_t q = *(const long2_t*)&hB[0][lrow * 256 + gsw];
            long b0_ = *(const long*)(WfcP + (((size_t)w * 8 + 2 * kbh) * 64 + lane) * 8);
            long b1_ = *(const long*)(WfcP + (((size_t)w * 8 + 2 * kbh + 1) * 64 + lane) * 8);
            a = __builtin_amdgcn_mfma_f32_16x16x32_fp8_fp8(q.x, b0_, a, 0, 0, 0);
            a = __builtin_amdgcn_mfma_f32_16x16x32_fp8_fp8(q.y, b1_, a, 0, 0, 0);
        }
        const int col = w * 16 + lrow;
        if (col < NK) {
            float bb = bfc[col];
            #pragma unroll
            for (int r = 0; r < 4; ++r)
                out[(size_t)(k * 16 + kgrp * 4 + r) * NK + col] = a[r] * INV_SC + bb;
        }
    }
}

// ---------------- IDM rollout (exact fp32) ----------------
__global__ void k_idm(const float* __restrict__ x, const float* __restrict__ s0,
                      const float* __restrict__ vl, float* __restrict__ out) {
    int b = blockIdx.x * 256 + threadIdx.x;
    if (b >= NB) return;
    float v = x[(size_t)b * NS * NI + (NS - 1) * NI + 0];
    float s = s0[b];
    float vlead = vl[b];
    const float den = 2.0f * sqrtf(A_MAX_ * B_SAFE_) + 1e-6f;
    float* o = out + (size_t)NB * NK + (size_t)b * NK;
    #pragma unroll 1
    for (int kk = 0; kk < NK; ++kk) {
        float dv = vlead - v;
        float sc = fmaxf(s, 1e-6f);
        float ss = fmaxf(S0_ + v * T_HW_ + v * dv / den, 0.0f);
        float a = A_MAX_ * (1.0f - v / V_DES_ - (ss / sc) * (ss / sc));
        v = fmaxf(v + DT_ * a, 0.0f);
        s = fmaxf(s + dv * DT_, 1e-6f);
        o[kk] = v;
    }
}

// ---------------- launch ----------------
extern "C" void kernel_launch(void* const* d_in, const int* in_sizes, int n_in,
                              void* d_out, int out_size, void* d_ws, size_t ws_size,
                              hipStream_t stream) {
    const float* x    = (const float*)d_in[0];
    const float* s0   = (const float*)d_in[1];
    const float* vl   = (const float*)d_in[2];
    const float* Wih0 = (const float*)d_in[3];
    const float* Whh0 = (const float*)d_in[4];
    const float* bih0 = (const float*)d_in[5];
    const float* bhh0 = (const float*)d_in[6];
    const float* Wih1 = (const float*)d_in[7];
    const float* Whh1 = (const float*)d_in[8];
    const float* bih1 = (const float*)d_in[9];
    const float* bhh1 = (const float*)d_in[10];
    const float* Wfc  = (const float*)d_in[11];
    const float* bfc  = (const float*)d_in[12];
    float* out = (float*)d_out;

    uint8_t* ws = (uint8_t*)d_ws;
    size_t off = 0;
    auto alloc = [&](size_t n) { uint8_t* p = ws + off; off += (n + 255) & ~(size_t)255; return p; };
    uint8_t* Wih0P = alloc(64 * 1 * 64 * 8);
    uint8_t* Whh0P = alloc(64 * 8 * 64 * 8);
    uint8_t* Wih1P = alloc(64 * 8 * 64 * 8);
    uint8_t* Whh1P = alloc(64 * 8 * 64 * 8);
    uint8_t* WfcP  = alloc(4 * 8 * 64 * 8);
    float* b0 = (float*)alloc(NG * 4);
    float* b1 = (float*)alloc(NG * 4);
    uint8_t* x8 = alloc((size_t)NB * NS * NI);
    uint8_t* ring = alloc((size_t)128 * RING_D * 4096);   // 8 MB h0 stream
    uint*    ctrs = (uint*)alloc(128 * 32 * 4);

    k_pack<<<(64 * 1 * 64 + 255) / 256, 256, 0, stream>>>(Wih0, Wih0P, 64, 1, NG, NI);
    k_pack<<<(64 * 8 * 64 + 255) / 256, 256, 0, stream>>>(Whh0, Whh0P, 64, 8, NG, NH);
    k_pack<<<(64 * 8 * 64 + 255) / 256, 256, 0, stream>>>(Wih1, Wih1P, 64, 8, NG, NH);
    k_pack<<<(64 * 8 * 64 + 255) / 256, 256, 0, stream>>>(Whh1, Whh1P, 64, 8, NG, NH);
    k_pack<<<(4 * 8 * 64 + 255) / 256, 256, 0, stream>>>(Wfc, WfcP, 4, 8, NK, NH);
    k_bias<<<(2 * NG + 255) / 256, 256, 0, stream>>>(bih0, bhh0, bih1, bhh1, b0, b1);
    k_x8<<<(NB * NS * NI + 255) / 256, 256, 0, stream>>>(x, x8);
    hipMemsetAsync(ctrs, 0, 128 * 32 * 4, stream);

    k_lpipe<<<256, 512, 0, stream>>>(x8, Wih0P, Whh0P, Wih1P, Whh1P, WfcP,
                                     b0, b1, bfc, ring, ctrs, out);
    k_idm<<<(NB + 255) / 256, 256, 0, stream>>>(x, s0, vl, out);
}